// Round 14
// baseline (150.047 us; speedup 1.0000x reference)
//
#include <hip/hip_runtime.h>
#include <cstdint>

// Problem constants (from reference)
constexpr int B_   = 4096;
constexpr int T_   = 512;
constexpr int DIN  = 10;
constexpr int H_   = 20;
constexpr int DOUT = 2;

constexpr int SPW = 3;            // samples per wave (3 x 20 = 60 active lanes)
constexpr int CH  = 2;            // timesteps per x-chunk
constexpr int XV  = CH * DIN / 4; // float4 prefetch regs per chunk
constexpr int RS  = 48;           // LDS row stride in halves (96 B, 16B-aligned)

typedef float    v2f __attribute__((ext_vector_type(2)));
typedef float    v4f __attribute__((ext_vector_type(4)));
typedef _Float16 h2t __attribute__((ext_vector_type(2)));

constexpr float SCL = 2.885390082f;   // 2*log2(e): folded into weights/biases

__device__ __forceinline__ v2f pkfma(v2f a, v2f b, v2f c) {
    return __builtin_elementwise_fma(a, b, c);
}

// v_dot2_f32_f16: D = a.x*b.x + a.y*b.y + c (f32 accumulate, one instr)
__device__ __forceinline__ float fdot2(h2t a, h2t b, float c) {
#if __has_builtin(__builtin_amdgcn_fdot2)
    return __builtin_amdgcn_fdot2(a, b, c, false);
#else
    return fmaf((float)a.x, (float)b.x, fmaf((float)a.y, (float)b.y, c));
#endif
}

// tanh from PRE-SCALED input s = 2*log2e*v: e=exp2(s); 1-2/(e+1). 4-op chain.
__device__ __forceinline__ float tanh_pre(float s) {
    float e = __builtin_amdgcn_exp2f(s);
    float r = __builtin_amdgcn_rcpf(e + 1.0f);
    return fmaf(-2.0f, r, 1.0f);
}

union V4H { v4f f; h2t h[4]; };
union V2H { v2f f; h2t h[2]; };

// Skewed 2-layer RNN, f16 state, chain-optimized:
//  - padded row [h1(20) | pad | h2(20)] (96 B): h1 subrow read issues right
//    after the h1 write (not blocked behind h2's write)
//  - 4 accumulator chains in every dot (depth 10 -> 5 for L1)
//  - weights pre-scaled by 2*log2e: tanh loses its leading multiply
extern "C" __global__ void __launch_bounds__(64, 1)
rnn_h16b(const float* __restrict__ x,
         const float* __restrict__ w_ih0, const float* __restrict__ w_hh0,
         const float* __restrict__ b_ih0, const float* __restrict__ b_hh0,
         const float* __restrict__ w_ih1, const float* __restrict__ w_hh1,
         const float* __restrict__ b_ih1, const float* __restrict__ b_hh1,
         const float* __restrict__ fc_w, const float* __restrict__ fc_b,
         float* __restrict__ out)
{
    const int lane = threadIdx.x;
    const int sl   = lane / H_;          // 0..2 active, 3 = idle lanes 60..63
    const int i    = lane - sl * H_;     // h-index 0..19
    const int samp = blockIdx.x * SPW + sl;
    const int sc   = (samp < B_) ? samp : (B_ - 1);   // clamped for safe loads
    const int slc  = (sl < SPW) ? sl : SPW;           // idle lanes -> spare row

    __shared__ __align__(16) _Float16 hs[(SPW + 1) * RS];
    _Float16* row = &hs[slc * RS];       // [0..19]=h1, [24..43]=h2

    // ---- per-lane weight rows as f16 pairs, PRE-SCALED by 2*log2e ----
    h2t wh0h[10], wi1h[10], wh1h[10];
    {
        const v4f* p0 = reinterpret_cast<const v4f*>(w_hh0 + i * H_);
        const v4f* p1 = reinterpret_cast<const v4f*>(w_ih1 + i * H_);
        const v4f* p2 = reinterpret_cast<const v4f*>(w_hh1 + i * H_);
        #pragma unroll
        for (int k = 0; k < 5; ++k) {
            v4f a = p0[k];
            wh0h[2*k]   = h2t{(_Float16)(a.x*SCL), (_Float16)(a.y*SCL)};
            wh0h[2*k+1] = h2t{(_Float16)(a.z*SCL), (_Float16)(a.w*SCL)};
            v4f b = p1[k];
            wi1h[2*k]   = h2t{(_Float16)(b.x*SCL), (_Float16)(b.y*SCL)};
            wi1h[2*k+1] = h2t{(_Float16)(b.z*SCL), (_Float16)(b.w*SCL)};
            v4f c = p2[k];
            wh1h[2*k]   = h2t{(_Float16)(c.x*SCL), (_Float16)(c.y*SCL)};
            wh1h[2*k+1] = h2t{(_Float16)(c.z*SCL), (_Float16)(c.w*SCL)};
        }
    }
    // x-projection weights (f32, pre-scaled)
    v2f wi0p[DIN / 2];
    {
        const v2f* p = reinterpret_cast<const v2f*>(w_ih0 + i * DIN);
        #pragma unroll
        for (int k = 0; k < DIN / 2; ++k) {
            v2f v = p[k];
            wi0p[k] = (v2f){v.x * SCL, v.y * SCL};
        }
    }
    const float bias0 = (b_ih0[i] + b_hh0[i]) * SCL;
    const float bias1 = (b_ih1[i] + b_hh1[i]) * SCL;

    // ---- gathered state: h1h = h1(tau-1), h2h = h2(tau-2) ----
    h2t h1h[10], h2h[10];
    #pragma unroll
    for (int k = 0; k < 10; ++k) {
        h1h[k] = h2t{(_Float16)0.f, (_Float16)0.f};
        h2h[k] = h2t{(_Float16)0.f, (_Float16)0.f};
    }

    const v4f* xb = reinterpret_cast<const v4f*>(x + (size_t)sc * (T_ * DIN));

    v4f xv[XV];
    #pragma unroll
    for (int k = 0; k < XV; ++k) xv[k] = xb[k];

    auto getpair = [&](int p) -> v2f {
        v4f v = xv[p >> 1];
        return (p & 1) ? (v2f){v.z, v.w} : (v2f){v.x, v.y};
    };

    auto consume_xp = [&](float (&xp)[CH]) {
        #pragma unroll
        for (int m = 0; m < CH; ++m) {
            v2f acc = (v2f){bias0, 0.f};
            #pragma unroll
            for (int q = 0; q < DIN / 2; ++q)
                acc = pkfma(getpair(m * (DIN / 2) + q), wi0p[q], acc);
            xp[m] = acc.x + acc.y;
        }
    };

    // subrow reads (issue-early; consumed next use, waits land late)
    auto read_h1 = [&](V4H& r0, V4H& r1, V2H& r2) {
        r0.f = *reinterpret_cast<const v4f*>(row + 0);   // h1[0..7]
        r1.f = *reinterpret_cast<const v4f*>(row + 8);   // h1[8..15]
        r2.f = *reinterpret_cast<const v2f*>(row + 16);  // h1[16..19]
    };
    auto read_h2 = [&](V4H& r0, V4H& r1, V2H& r2) {
        r0.f = *reinterpret_cast<const v4f*>(row + 24);
        r1.f = *reinterpret_cast<const v4f*>(row + 32);
        r2.f = *reinterpret_cast<const v2f*>(row + 40);
    };
    auto commit = [&](h2t (&dst)[10], const V4H& r0, const V4H& r1, const V2H& r2) {
        dst[0]=r0.h[0]; dst[1]=r0.h[1]; dst[2]=r0.h[2]; dst[3]=r0.h[3];
        dst[4]=r1.h[0]; dst[5]=r1.h[1]; dst[6]=r1.h[2]; dst[7]=r1.h[3];
        dst[8]=r2.h[0]; dst[9]=r2.h[1];
    };

    // one skewed step: h1(tau) [L0], h2(tau-1) [L1]; split exchange
    auto full_step = [&](float xpm) {
        // ---- L0: 10 dot2, 4 chains (depth 3) ----
        float a0 = xpm, a1 = 0.f, a2 = 0.f, a3 = 0.f;
        #pragma unroll
        for (int k = 0; k < 8; k += 4) {
            a0 = fdot2(h1h[k+0], wh0h[k+0], a0);
            a1 = fdot2(h1h[k+1], wh0h[k+1], a1);
            a2 = fdot2(h1h[k+2], wh0h[k+2], a2);
            a3 = fdot2(h1h[k+3], wh0h[k+3], a3);
        }
        a0 = fdot2(h1h[8], wh0h[8], a0);
        a1 = fdot2(h1h[9], wh0h[9], a1);
        float h1n = tanh_pre((a0 + a1) + (a2 + a3));

        // ---- h1 exchange: write, read subrow IMMEDIATELY ----
        row[i] = (_Float16)h1n;
        V4H n10, n11; V2H n12;
        read_h1(n10, n11, n12);

        // ---- L1 (old regs; covers h1 RT): 20 dot2, 4 chains (depth 5) ----
        float b0 = bias1, b1 = 0.f, b2 = 0.f, b3 = 0.f;
        #pragma unroll
        for (int k = 0; k < 8; k += 4) {
            b0 = fdot2(h1h[k+0], wi1h[k+0], b0);
            b1 = fdot2(h1h[k+1], wi1h[k+1], b1);
            b2 = fdot2(h1h[k+2], wi1h[k+2], b2);
            b3 = fdot2(h1h[k+3], wi1h[k+3], b3);
        }
        b0 = fdot2(h1h[8], wi1h[8], b0);
        b1 = fdot2(h1h[9], wi1h[9], b1);
        #pragma unroll
        for (int k = 0; k < 8; k += 4) {
            b2 = fdot2(h2h[k+0], wh1h[k+0], b2);
            b3 = fdot2(h2h[k+1], wh1h[k+1], b3);
            b0 = fdot2(h2h[k+2], wh1h[k+2], b0);
            b1 = fdot2(h2h[k+3], wh1h[k+3], b1);
        }
        b2 = fdot2(h2h[8], wh1h[8], b2);
        b3 = fdot2(h2h[9], wh1h[9], b3);
        float h2n = tanh_pre((b0 + b1) + (b2 + b3));

        // ---- h2 exchange: write, read subrow (covered by next L0) ----
        row[24 + i] = (_Float16)h2n;
        V4H n20, n21; V2H n22;
        read_h2(n20, n21, n22);

        // ---- commit (register renames) ----
        commit(h1h, n10, n11, n12);
        commit(h2h, n20, n21, n22);
    };

    // ---- chunk 0, tau=0 peeled: h1(0)=tanh(xp[0]); h2 row zeroed ----
    {
        float xp[CH];
        consume_xp(xp);
        #pragma unroll
        for (int k = 0; k < XV; ++k) xv[k] = xb[(CH * DIN) / 4 + k];

        float h1n = tanh_pre(xp[0]);
        row[i]      = (_Float16)h1n;
        row[24 + i] = (_Float16)0.f;
        V4H n10, n11; V2H n12;
        read_h1(n10, n11, n12);
        commit(h1h, n10, n11, n12);

        #pragma unroll
        for (int m = 1; m < CH; ++m) full_step(xp[m]);
    }

    // ---- main loop ----
    for (int t0 = CH; t0 < T_; t0 += CH) {
        float xp[CH];
        consume_xp(xp);
        {
            const int t0n = (t0 + CH < T_) ? (t0 + CH) : 0;
            #pragma unroll
            for (int k = 0; k < XV; ++k) xv[k] = xb[(t0n * DIN) / 4 + k];
        }
        #pragma unroll
        for (int m = 0; m < CH; ++m) full_step(xp[m]);
    }

    // ---- epilogue: h2(T-1) from h1(T-1) (=h1h) and h2(T-2) (=h2h) ----
    float h2fin[H_];
    {
        float b0 = bias1, b1 = 0.f, b2 = 0.f, b3 = 0.f;
        #pragma unroll
        for (int k = 0; k < 8; k += 4) {
            b0 = fdot2(h1h[k+0], wi1h[k+0], b0);
            b1 = fdot2(h1h[k+1], wi1h[k+1], b1);
            b2 = fdot2(h1h[k+2], wi1h[k+2], b2);
            b3 = fdot2(h1h[k+3], wi1h[k+3], b3);
        }
        b0 = fdot2(h1h[8], wi1h[8], b0);
        b1 = fdot2(h1h[9], wi1h[9], b1);
        #pragma unroll
        for (int k = 0; k < 8; k += 4) {
            b2 = fdot2(h2h[k+0], wh1h[k+0], b2);
            b3 = fdot2(h2h[k+1], wh1h[k+1], b3);
            b0 = fdot2(h2h[k+2], wh1h[k+2], b0);
            b1 = fdot2(h2h[k+3], wh1h[k+3], b1);
        }
        b2 = fdot2(h2h[8], wh1h[8], b2);
        b3 = fdot2(h2h[9], wh1h[9], b3);
        float h2n = tanh_pre((b0 + b1) + (b2 + b3));
        row[24 + i] = (_Float16)h2n;
        #pragma unroll
        for (int j = 0; j < H_; ++j) h2fin[j] = (float)row[24 + j];
    }

    // ---- FC (unscaled fc_w; h2fin are true tanh outputs) ----
    if (sl < SPW && samp < B_ && i < DOUT) {
        float acc = fc_b[i];
        #pragma unroll
        for (int j = 0; j < H_; ++j) acc = fmaf(h2fin[j], fc_w[i * H_ + j], acc);
        out[samp * DOUT + i] = acc;
    }
}

extern "C" void kernel_launch(void* const* d_in, const int* in_sizes, int n_in,
                              void* d_out, int out_size, void* d_ws, size_t ws_size,
                              hipStream_t stream) {
    (void)in_sizes; (void)n_in; (void)d_ws; (void)ws_size; (void)out_size;
    const float* x     = (const float*)d_in[0];
    const float* w_ih0 = (const float*)d_in[1];
    const float* w_hh0 = (const float*)d_in[2];
    const float* b_ih0 = (const float*)d_in[3];
    const float* b_hh0 = (const float*)d_in[4];
    const float* w_ih1 = (const float*)d_in[5];
    const float* w_hh1 = (const float*)d_in[6];
    const float* b_ih1 = (const float*)d_in[7];
    const float* b_hh1 = (const float*)d_in[8];
    const float* fc_w  = (const float*)d_in[9];
    const float* fc_b  = (const float*)d_in[10];
    float* out = (float*)d_out;

    const int grid = (B_ + SPW - 1) / SPW;   // 1366 single-wave blocks
    hipLaunchKernelGGL(rnn_h16b, dim3(grid), dim3(64), 0, stream,
                       x, w_ih0, w_hh0, b_ih0, b_hh0,
                       w_ih1, w_hh1, b_ih1, b_hh1, fc_w, fc_b, out);
}